// Round 5
// baseline (461.247 us; speedup 1.0000x reference)
//
#include <hip/hip_runtime.h>
#include <math.h>

constexpr int NODES = 100000;
constexpr int F = 64;       // features
constexpr int C = 40;       // classes
constexpr int NRANGE = 8;                    // one node-range per XCD
constexpr int RNODES = NODES / NRANGE;       // 12500
constexpr int CAPR = 240000;                 // per-range edge capacity (mean 200k, sigma ~420)
constexpr int SCAN_BLOCKS = 2048;            // 256 blocks per range
constexpr int AGG_BLOCKS = 2048;

// ===========================================================================
// Pass 1: per-range histogram. blockIdx&7 -> XCD (round-robin heuristic);
// each range scans the full dst stream (L3-served) and atomics only its own
// 50KB degi slice -> XCD-L2-local atomics, full-line writebacks.
// ===========================================================================
__global__ __launch_bounds__(256)
void hist_v2(const int* __restrict__ dst, int* __restrict__ degi, int nedges) {
    int g = blockIdx.x & 7;
    int lo = g * RNODES, hi = lo + RNODES;
    int stride = (SCAN_BLOCKS >> 3) * 256;
    for (int e = (blockIdx.x >> 3) * 256 + threadIdx.x; e < nedges; e += stride) {
        int d = dst[e];
        if (d >= lo && d < hi) atomicAdd(&degi[d], 1);
    }
}

// ===========================================================================
// Pass 2: ticket offsets, range-local so each range's edges occupy the
// contiguous region [g*CAPR, g*CAPR+CAPR).
// ===========================================================================
__global__ __launch_bounds__(256)
void offsets_v2(const int* __restrict__ degi, int* __restrict__ rcount,
                int* __restrict__ off, int* __restrict__ cursor) {
    int g = blockIdx.x & 7;
    int i = (blockIdx.x >> 3) * 256 + threadIdx.x;
    if (i >= RNODES) return;
    int n = g * RNODES + i;
    int dgr = degi[n];
    int p = atomicAdd(&rcount[g], dgr);
    int o = g * CAPR + min(p, CAPR - 1);
    off[n] = o;
    cursor[n] = o;
}

// ===========================================================================
// Pass 3: binning scatter, range-partitioned. Cursors + destination region
// for range g are XCD-g L2-resident -> dense line assembly, no partial-line
// cross-XCD writebacks.
// ===========================================================================
__global__ __launch_bounds__(256)
void bin_v3(const int* __restrict__ src, const int* __restrict__ dst,
            int* __restrict__ cursor, int* __restrict__ sorted_src, int nedges) {
    int g = blockIdx.x & 7;
    int lo = g * RNODES, hi = lo + RNODES;
    int rend = g * CAPR + CAPR;
    int stride = (SCAN_BLOCKS >> 3) * 256;
    for (int e = (blockIdx.x >> 3) * 256 + threadIdx.x; e < nedges; e += stride) {
        int d = dst[e];
        int s = src[e];
        if (d >= lo && d < hi) {
            int p = atomicAdd(&cursor[d], 1);
            if (p < rend) sorted_src[p] = s;
        }
    }
}

__device__ inline void f4add(float4& a, const float4 b) {
    a.x += b.x; a.y += b.y; a.z += b.z; a.w += b.w;
}
__device__ inline float4 f4shfl_xor(float4 v, int m) {
    float4 r;
    r.x = __shfl_xor(v.x, m);
    r.y = __shfl_xor(v.y, m);
    r.z = __shfl_xor(v.z, m);
    r.w = __shfl_xor(v.w, m);
    return r;
}

// ===========================================================================
// Pass 4 (fused): wave-per-node gather-mean + GEMVs + log_softmax.
// Grid-stride so the 20.6KB weight staging is amortized (~49 node-groups per
// block). blockIdx&7 pins each node range to its XCD (sorted_src L2-local).
// ===========================================================================
__global__ __launch_bounds__(256)
void aggregate_fused(const float* __restrict__ x,
                     const int* __restrict__ sorted_src,
                     const int* __restrict__ off,
                     const int* __restrict__ degi,
                     const float* __restrict__ wl,
                     const float* __restrict__ bl,
                     const float* __restrict__ wr,
                     float* __restrict__ out) {
    __shared__ float sWl[F * C];
    __shared__ float sWr[F * C];
    __shared__ float sb[C];
    for (int i = threadIdx.x; i < F * C; i += 256) { sWl[i] = wl[i]; sWr[i] = wr[i]; }
    if (threadIdx.x < C) sb[threadIdx.x] = bl[threadIdx.x];
    __syncthreads();   // LDS read-only afterwards; waves independent below

    int t = threadIdx.x;
    int lane = t & 63;
    int wave = t >> 6;
    int g = lane >> 4;      // edge group 0..3
    int q = lane & 15;      // float4 slot
    int range = blockIdx.x & 7;
    int kb = blockIdx.x >> 3;                 // 0..255 within range
    const int GROUPS = RNODES / 4;            // 3125 node-groups per range

    const float4* x4 = (const float4*)x;

    for (int k = kb; k < GROUPS; k += (AGG_BLOCKS >> 3)) {
        int n = range * RNODES + k * 4 + wave;
        int base = off[n];
        int cnt  = degi[n];

        float4 a0 = make_float4(0.f, 0.f, 0.f, 0.f);
        float4 a1 = a0, a2 = a0, a3 = a0;

        int j = 0;
        for (; j + 16 <= cnt; j += 16) {      // 16 rows in flight per wave
            int s0 = sorted_src[base + j +      g];
            int s1 = sorted_src[base + j +  4 + g];
            int s2 = sorted_src[base + j +  8 + g];
            int s3 = sorted_src[base + j + 12 + g];
            float4 v0 = x4[(size_t)s0 * 16 + q];
            float4 v1 = x4[(size_t)s1 * 16 + q];
            float4 v2 = x4[(size_t)s2 * 16 + q];
            float4 v3 = x4[(size_t)s3 * 16 + q];
            f4add(a0, v0); f4add(a1, v1); f4add(a2, v2); f4add(a3, v3);
        }
        for (; j < cnt; j += 4) {             // masked tail, 4 rows/iter
            int e = j + g;
            if (e < cnt) {
                int s = sorted_src[base + e];
                f4add(a0, x4[(size_t)s * 16 + q]);
            }
        }
        f4add(a0, a1); f4add(a2, a3); f4add(a0, a2);
        f4add(a0, f4shfl_xor(a0, 16));
        f4add(a0, f4shfl_xor(a0, 32));
        // now every lane with slot q holds sum of features [4q,4q+4)

        float inv = 1.0f / (float)max(cnt, 1);
        float4 xv = x4[(size_t)n * 16 + q];   // root features, same slot layout

        // ---- epilogue: lane c (<40) computes out[n][c] ----
        int c = lane;
        float oacc = (c < C) ? sb[c] : 0.0f;
        int cc = (c < C) ? c : 0;
#pragma unroll
        for (int qq = 0; qq < 16; ++qq) {
            float m0 = __shfl(a0.x, qq) * inv;
            float m1 = __shfl(a0.y, qq) * inv;
            float m2 = __shfl(a0.z, qq) * inv;
            float m3 = __shfl(a0.w, qq) * inv;
            float r0 = __shfl(xv.x, qq);
            float r1 = __shfl(xv.y, qq);
            float r2 = __shfl(xv.z, qq);
            float r3 = __shfl(xv.w, qq);
            int f = qq * 4;
            oacc = fmaf(m0, sWl[(f + 0) * C + cc], oacc);
            oacc = fmaf(r0, sWr[(f + 0) * C + cc], oacc);
            oacc = fmaf(m1, sWl[(f + 1) * C + cc], oacc);
            oacc = fmaf(r1, sWr[(f + 1) * C + cc], oacc);
            oacc = fmaf(m2, sWl[(f + 2) * C + cc], oacc);
            oacc = fmaf(r2, sWr[(f + 2) * C + cc], oacc);
            oacc = fmaf(m3, sWl[(f + 3) * C + cc], oacc);
            oacc = fmaf(r3, sWr[(f + 3) * C + cc], oacc);
        }

        // log_softmax across the 40 class lanes
        float mv = (c < C) ? oacc : -1e30f;
#pragma unroll
        for (int d = 32; d >= 1; d >>= 1) mv = fmaxf(mv, __shfl_xor(mv, d));
        float ev = (c < C) ? __expf(oacc - mv) : 0.0f;
        float sv = ev;
#pragma unroll
        for (int d = 32; d >= 1; d >>= 1) sv += __shfl_xor(sv, d);
        float lse = mv + __logf(sv);

        if (c < C) out[(size_t)n * C + c] = oacc - lse;
    }
}

// ===========================================================================
// Fallback path (atomic scatter + separate node kernel) if ws too small
// ===========================================================================
__global__ __launch_bounds__(256)
void scatter_kernel(const float* __restrict__ x,
                    const int* __restrict__ src,
                    const int* __restrict__ dst,
                    float* __restrict__ aggsum,
                    float* __restrict__ deg,
                    int nedges) {
    int lane = threadIdx.x & 63;
    int e = blockIdx.x * 4 + (threadIdx.x >> 6);
    if (e >= nedges) return;
    int s = src[e];
    int d = dst[e];
    if ((unsigned)s >= (unsigned)NODES || (unsigned)d >= (unsigned)NODES) return;
    float v = x[(size_t)s * F + lane];
    atomicAdd(&aggsum[(size_t)d * F + lane], v);
    if (lane == 0) atomicAdd(&deg[d], 1.0f);
}

__global__ __launch_bounds__(256)
void meanify_kernel(float* __restrict__ aggsum, const float* __restrict__ deg) {
    int lane = threadIdx.x & 63;
    int n = blockIdx.x * 4 + (threadIdx.x >> 6);
    if (n >= NODES) return;
    float inv = 1.0f / fmaxf(deg[n], 1.0f);
    aggsum[(size_t)n * F + lane] *= inv;
}

__global__ __launch_bounds__(256)
void node_kernel(const float* __restrict__ x,
                 const float* __restrict__ aggmean,
                 const float* __restrict__ wl,
                 const float* __restrict__ bl,
                 const float* __restrict__ wr,
                 float* __restrict__ out) {
    __shared__ alignas(16) float sWl[F * C];
    __shared__ alignas(16) float sWr[F * C];
    __shared__ alignas(16) float sb[C];
    for (int i = threadIdx.x; i < F * C; i += 256) { sWl[i] = wl[i]; sWr[i] = wr[i]; }
    if (threadIdx.x < C) sb[threadIdx.x] = bl[threadIdx.x];
    __syncthreads();
    int n = blockIdx.x * 256 + threadIdx.x;
    if (n >= NODES) return;
    float4 acc[10];
    const float4* sb4 = (const float4*)sb;
#pragma unroll
    for (int qq = 0; qq < 10; ++qq) acc[qq] = sb4[qq];
    const float4* xr  = (const float4*)(x       + (size_t)n * F);
    const float4* ar  = (const float4*)(aggmean + (size_t)n * F);
    const float4* wl4 = (const float4*)sWl;
    const float4* wr4 = (const float4*)sWr;
    for (int f4 = 0; f4 < F / 4; ++f4) {
        float4 xvv = xr[f4];
        float4 avv = ar[f4];
        float xs[4]  = {xvv.x, xvv.y, xvv.z, xvv.w};
        float as_[4] = {avv.x, avv.y, avv.z, avv.w};
#pragma unroll
        for (int jj = 0; jj < 4; ++jj) {
            int f = f4 * 4 + jj;
#pragma unroll
            for (int qq = 0; qq < 10; ++qq) {
                float4 wlv = wl4[f * 10 + qq];
                float4 wrv = wr4[f * 10 + qq];
                acc[qq].x = fmaf(as_[jj], wlv.x, fmaf(xs[jj], wrv.x, acc[qq].x));
                acc[qq].y = fmaf(as_[jj], wlv.y, fmaf(xs[jj], wrv.y, acc[qq].y));
                acc[qq].z = fmaf(as_[jj], wlv.z, fmaf(xs[jj], wrv.z, acc[qq].z));
                acc[qq].w = fmaf(as_[jj], wlv.w, fmaf(xs[jj], wrv.w, acc[qq].w));
            }
        }
    }
    float m = -1e30f;
#pragma unroll
    for (int qq = 0; qq < 10; ++qq)
        m = fmaxf(m, fmaxf(fmaxf(acc[qq].x, acc[qq].y), fmaxf(acc[qq].z, acc[qq].w)));
    float ssum = 0.0f;
#pragma unroll
    for (int qq = 0; qq < 10; ++qq)
        ssum += __expf(acc[qq].x - m) + __expf(acc[qq].y - m) +
                __expf(acc[qq].z - m) + __expf(acc[qq].w - m);
    float lse = m + __logf(ssum);
    float4* op = (float4*)(out + (size_t)n * C);
#pragma unroll
    for (int qq = 0; qq < 10; ++qq) {
        float4 v;
        v.x = acc[qq].x - lse; v.y = acc[qq].y - lse;
        v.z = acc[qq].z - lse; v.w = acc[qq].w - lse;
        op[qq] = v;
    }
}

extern "C" void kernel_launch(void* const* d_in, const int* in_sizes, int n_in,
                              void* d_out, int out_size, void* d_ws, size_t ws_size,
                              hipStream_t stream) {
    const float* x     = (const float*)d_in[0];
    const int*   index = (const int*)d_in[1];
    const float* wl    = (const float*)d_in[2];
    const float* bl    = (const float*)d_in[3];
    const float* wr    = (const float*)d_in[4];
    float* out = (float*)d_out;

    int nedges = in_sizes[1] / 2;
    const int* src = index;
    const int* dst = index + nedges;

    // ws layout: [degi N][rcount 8][off N][cursor N][sorted_src 8*CAPR]
    size_t need = ((size_t)3 * NODES + 8 + (size_t)NRANGE * CAPR) * 4;

    if (ws_size >= need) {
        int* degi       = (int*)d_ws;
        int* rcount     = degi + NODES;
        int* off        = rcount + NRANGE;
        int* cursor     = off + NODES;
        int* sorted_src = cursor + NODES;

        hipMemsetAsync(degi, 0, (size_t)(NODES + NRANGE) * sizeof(int), stream);

        hist_v2<<<SCAN_BLOCKS, 256, 0, stream>>>(dst, degi, nedges);
        offsets_v2<<<8 * ((RNODES + 255) / 256), 256, 0, stream>>>(
            degi, rcount, off, cursor);
        bin_v3<<<SCAN_BLOCKS, 256, 0, stream>>>(src, dst, cursor, sorted_src, nedges);
        aggregate_fused<<<AGG_BLOCKS, 256, 0, stream>>>(
            x, sorted_src, off, degi, wl, bl, wr, out);
    } else {
        float* aggsum = (float*)d_ws;
        float* deg    = aggsum + (size_t)NODES * F;
        size_t zbytes = ((size_t)NODES * F + (size_t)NODES) * sizeof(float);
        hipMemsetAsync(d_ws, 0, zbytes, stream);

        int nblk4 = (nedges + 3) / 4;
        scatter_kernel<<<nblk4, 256, 0, stream>>>(x, src, dst, aggsum, deg, nedges);
        meanify_kernel<<<(NODES + 3) / 4, 256, 0, stream>>>(aggsum, deg);
        node_kernel<<<(NODES + 255) / 256, 256, 0, stream>>>(
            x, aggsum, wl, bl, wr, out);
    }
}

// Round 6
// 259.695 us; speedup vs baseline: 1.7761x; 1.7761x over previous
//
#include <hip/hip_runtime.h>
#include <math.h>

constexpr int NODES = 100000;
constexpr int F = 64;       // features
constexpr int C = 40;       // classes
constexpr int NPB   = 1024;                    // nodes per bucket
constexpr int NB    = (NODES + NPB - 1) / NPB; // 98 buckets
constexpr int NBPAD = 128;
constexpr int BCAP  = 20480;   // per-bucket edge cap (mean 16384, sigma ~127)
constexpr int TILE  = 4096;    // edges per bucketize block

// ===========================================================================
// K1: y = x @ Wl ; out(z) = x @ Wr + b.   (aggregation commutes with Wl)
// ===========================================================================
__global__ __launch_bounds__(256)
void precompute_yz(const float* __restrict__ x,
                   const float* __restrict__ wl,
                   const float* __restrict__ bl,
                   const float* __restrict__ wr,
                   float* __restrict__ y,
                   float* __restrict__ out) {
    __shared__ alignas(16) float sWl[F * C];
    __shared__ alignas(16) float sWr[F * C];
    __shared__ alignas(16) float sb[C];
    for (int i = threadIdx.x; i < F * C; i += 256) { sWl[i] = wl[i]; sWr[i] = wr[i]; }
    if (threadIdx.x < C) sb[threadIdx.x] = bl[threadIdx.x];
    __syncthreads();

    int n = blockIdx.x * 256 + threadIdx.x;
    if (n >= NODES) return;

    float4 ya[10], za[10];
    const float4* sb4 = (const float4*)sb;
#pragma unroll
    for (int q = 0; q < 10; ++q) {
        ya[q] = make_float4(0.f, 0.f, 0.f, 0.f);
        za[q] = sb4[q];
    }
    const float4* xr  = (const float4*)(x + (size_t)n * F);
    const float4* wl4 = (const float4*)sWl;
    const float4* wr4 = (const float4*)sWr;

    for (int f4 = 0; f4 < F / 4; ++f4) {
        float4 xv = xr[f4];
        float xs[4] = {xv.x, xv.y, xv.z, xv.w};
#pragma unroll
        for (int jj = 0; jj < 4; ++jj) {
            int f = f4 * 4 + jj;
            float xf = xs[jj];
#pragma unroll
            for (int q = 0; q < 10; ++q) {
                float4 wlv = wl4[f * 10 + q];
                float4 wrv = wr4[f * 10 + q];
                ya[q].x = fmaf(xf, wlv.x, ya[q].x);
                ya[q].y = fmaf(xf, wlv.y, ya[q].y);
                ya[q].z = fmaf(xf, wlv.z, ya[q].z);
                ya[q].w = fmaf(xf, wlv.w, ya[q].w);
                za[q].x = fmaf(xf, wrv.x, za[q].x);
                za[q].y = fmaf(xf, wrv.y, za[q].y);
                za[q].z = fmaf(xf, wrv.z, za[q].z);
                za[q].w = fmaf(xf, wrv.w, za[q].w);
            }
        }
    }
    float4* yp = (float4*)(y   + (size_t)n * C);   // n*160B, 16B aligned
    float4* zp = (float4*)(out + (size_t)n * C);
#pragma unroll
    for (int q = 0; q < 10; ++q) { yp[q] = ya[q]; zp[q] = za[q]; }
}

// ===========================================================================
// K2: bucketize edges by dst>>10 into NB dense streams.
// Tile-local LDS hist -> one global ticket per (tile,bucket) -> ~128B runs
// written by a single CU => full-line assembly, no partial-line churn.
// pack = src(17b) | dlow(10b)<<17
// ===========================================================================
__global__ __launch_bounds__(256)
void bucketize(const int* __restrict__ src, const int* __restrict__ dst,
               int* __restrict__ gcursor, int* __restrict__ bbuf, int nedges) {
    __shared__ int lhist[NBPAD];
    __shared__ int lcur[NBPAD];
    int t = threadIdx.x;
    for (int i = t; i < NBPAD; i += 256) lhist[i] = 0;
    __syncthreads();

    int base = blockIdx.x * TILE;
    int pk[16], bk[16];
#pragma unroll
    for (int u = 0; u < 16; ++u) {
        int e = base + u * 256 + t;
        bk[u] = -1;
        if (e < nedges) {
            int s = src[e], d = dst[e];
            if ((unsigned)s < (unsigned)NODES && (unsigned)d < (unsigned)NODES) {
                bk[u] = d >> 10;
                pk[u] = s | ((d & 1023) << 17);
                atomicAdd(&lhist[bk[u]], 1);
            }
        }
    }
    __syncthreads();
    if (t < NB) {
        int c = lhist[t];
        lcur[t] = c ? atomicAdd(&gcursor[t], c) : 0;   // bucket-relative base
    }
    __syncthreads();
#pragma unroll
    for (int u = 0; u < 16; ++u) {
        if (bk[u] >= 0) {
            int p = atomicAdd(&lcur[bk[u]], 1);
            if (p < BCAP) bbuf[(size_t)bk[u] * BCAP + p] = pk[u];
        }
    }
}

// ===========================================================================
// K4: one block per bucket: LDS hist over 1024 local dst -> block scan ->
// write deg/off densely -> scatter src into global dst-sorted CSR (65KB
// single-block window => single-CU line assembly).
// ===========================================================================
__global__ __launch_bounds__(256)
void local_sort(const int* __restrict__ bbuf, const int* __restrict__ gcount,
                int* __restrict__ sorted_src, int* __restrict__ off,
                int* __restrict__ deg) {
    __shared__ int lhist[NPB];
    __shared__ int lcur[NPB];
    __shared__ int wsum[4];
    __shared__ int sbase;

    int b = blockIdx.x;
    int t = threadIdx.x;
    int lane = t & 63, wv = t >> 6;

    // edge_base[b] = sum_{i<b} gcount[i]  (wave0 cooperative)
    if (t < 64) {
        int v = (t < b ? gcount[t] : 0) + (t + 64 < b ? gcount[t + 64] : 0);
#pragma unroll
        for (int d = 1; d < 64; d <<= 1) v += __shfl_xor(v, d);
        if (t == 0) sbase = v;
    }
    for (int i = t; i < NPB; i += 256) lhist[i] = 0;
    __syncthreads();

    int ebase = sbase;
    int cnt = gcount[b];
    if (cnt > BCAP) cnt = BCAP;
    const int* myb = bbuf + (size_t)b * BCAP;

    for (int i = t; i < cnt; i += 256)
        atomicAdd(&lhist[myb[i] >> 17], 1);
    __syncthreads();

    // block exclusive scan over 1024 counts (4 per thread)
    int c0 = lhist[4 * t], c1 = lhist[4 * t + 1];
    int c2 = lhist[4 * t + 2], c3 = lhist[4 * t + 3];
    int ts = c0 + c1 + c2 + c3;
    int sc = ts;
#pragma unroll
    for (int d = 1; d < 64; d <<= 1) {
        int o = __shfl_up(sc, d);
        if (lane >= d) sc += o;
    }
    if (lane == 63) wsum[wv] = sc;
    __syncthreads();
    int wpre = 0;
    for (int i = 0; i < wv; ++i) wpre += wsum[i];
    int excl = wpre + sc - ts;

    int o0 = ebase + excl;
    int o1 = o0 + c0, o2 = o1 + c1, o3 = o2 + c2;
    lcur[4 * t] = o0; lcur[4 * t + 1] = o1;
    lcur[4 * t + 2] = o2; lcur[4 * t + 3] = o3;

    int n0 = b * NPB + 4 * t;
    if (n0 + 3 < NODES) {
        *(int4*)(off + n0) = make_int4(o0, o1, o2, o3);
        *(int4*)(deg + n0) = make_int4(c0, c1, c2, c3);
    } else {
        if (n0     < NODES) { off[n0]     = o0; deg[n0]     = c0; }
        if (n0 + 1 < NODES) { off[n0 + 1] = o1; deg[n0 + 1] = c1; }
        if (n0 + 2 < NODES) { off[n0 + 2] = o2; deg[n0 + 2] = c2; }
        if (n0 + 3 < NODES) { off[n0 + 3] = o3; deg[n0 + 3] = c3; }
    }
    __syncthreads();

    for (int i = t; i < cnt; i += 256) {
        int pk = myb[i];
        int p = atomicAdd(&lcur[pk >> 17], 1);
        sorted_src[p] = pk & 0x1FFFF;
    }
}

// ===========================================================================
// K5: wave per node, lane = class. Gather y[src] rows (160B, 3 lines),
// unroll-8 predicated (no serial tail), add z (in out), log_softmax.
// ===========================================================================
__global__ __launch_bounds__(256)
void aggregate_y(const float* __restrict__ y,
                 const int* __restrict__ sorted_src,
                 const int* __restrict__ off,
                 const int* __restrict__ deg,
                 float* __restrict__ out) {
    int t = threadIdx.x;
    int lane = t & 63;
    int n = blockIdx.x * 4 + (t >> 6);
    if (n >= NODES) return;

    int base = off[n];
    int cnt  = deg[n];
    int cc = lane < C ? lane : C - 1;

    float acc = 0.0f;
    for (int j = 0; j < cnt; j += 8) {
#pragma unroll
        for (int u = 0; u < 8; ++u) {
            int e = j + u;
            int ec = e < cnt ? e : cnt - 1;
            int s = sorted_src[base + ec];       // wave-uniform broadcast load
            float v = y[(size_t)s * C + cc];     // 40 lanes -> 160B row
            acc += (e < cnt) ? v : 0.0f;
        }
    }
    float inv = 1.0f / (float)(cnt > 0 ? cnt : 1);

    float o = 0.0f;
    if (lane < C) o = out[(size_t)n * C + lane] + acc * inv;  // z + mean@Wl

    float mv = lane < C ? o : -1e30f;
#pragma unroll
    for (int d = 1; d < 64; d <<= 1) mv = fmaxf(mv, __shfl_xor(mv, d));
    float ev = lane < C ? __expf(o - mv) : 0.0f;
#pragma unroll
    for (int d = 1; d < 64; d <<= 1) ev += __shfl_xor(ev, d);
    float lse = mv + __logf(ev);

    if (lane < C) out[(size_t)n * C + lane] = o - lse;
}

// ===========================================================================
// Fallback path (R1) if workspace too small
// ===========================================================================
__global__ __launch_bounds__(256)
void scatter_kernel(const float* __restrict__ x, const int* __restrict__ src,
                    const int* __restrict__ dst, float* __restrict__ aggsum,
                    float* __restrict__ deg, int nedges) {
    int lane = threadIdx.x & 63;
    int e = blockIdx.x * 4 + (threadIdx.x >> 6);
    if (e >= nedges) return;
    int s = src[e], d = dst[e];
    if ((unsigned)s >= (unsigned)NODES || (unsigned)d >= (unsigned)NODES) return;
    atomicAdd(&aggsum[(size_t)d * F + lane], x[(size_t)s * F + lane]);
    if (lane == 0) atomicAdd(&deg[d], 1.0f);
}

__global__ __launch_bounds__(256)
void meanify_kernel(float* __restrict__ aggsum, const float* __restrict__ deg) {
    int lane = threadIdx.x & 63;
    int n = blockIdx.x * 4 + (threadIdx.x >> 6);
    if (n >= NODES) return;
    aggsum[(size_t)n * F + lane] *= 1.0f / fmaxf(deg[n], 1.0f);
}

__global__ __launch_bounds__(256)
void node_kernel(const float* __restrict__ x, const float* __restrict__ aggmean,
                 const float* __restrict__ wl, const float* __restrict__ bl,
                 const float* __restrict__ wr, float* __restrict__ out) {
    __shared__ alignas(16) float sWl[F * C];
    __shared__ alignas(16) float sWr[F * C];
    __shared__ alignas(16) float sb[C];
    for (int i = threadIdx.x; i < F * C; i += 256) { sWl[i] = wl[i]; sWr[i] = wr[i]; }
    if (threadIdx.x < C) sb[threadIdx.x] = bl[threadIdx.x];
    __syncthreads();
    int n = blockIdx.x * 256 + threadIdx.x;
    if (n >= NODES) return;
    float4 acc[10];
    const float4* sb4 = (const float4*)sb;
#pragma unroll
    for (int q = 0; q < 10; ++q) acc[q] = sb4[q];
    const float4* xr  = (const float4*)(x       + (size_t)n * F);
    const float4* ar  = (const float4*)(aggmean + (size_t)n * F);
    const float4* wl4 = (const float4*)sWl;
    const float4* wr4 = (const float4*)sWr;
    for (int f4 = 0; f4 < F / 4; ++f4) {
        float4 xv = xr[f4], av = ar[f4];
        float xs[4]  = {xv.x, xv.y, xv.z, xv.w};
        float as_[4] = {av.x, av.y, av.z, av.w};
#pragma unroll
        for (int jj = 0; jj < 4; ++jj) {
            int f = f4 * 4 + jj;
#pragma unroll
            for (int q = 0; q < 10; ++q) {
                float4 wlv = wl4[f * 10 + q], wrv = wr4[f * 10 + q];
                acc[q].x = fmaf(as_[jj], wlv.x, fmaf(xs[jj], wrv.x, acc[q].x));
                acc[q].y = fmaf(as_[jj], wlv.y, fmaf(xs[jj], wrv.y, acc[q].y));
                acc[q].z = fmaf(as_[jj], wlv.z, fmaf(xs[jj], wrv.z, acc[q].z));
                acc[q].w = fmaf(as_[jj], wlv.w, fmaf(xs[jj], wrv.w, acc[q].w));
            }
        }
    }
    float m = -1e30f;
#pragma unroll
    for (int q = 0; q < 10; ++q)
        m = fmaxf(m, fmaxf(fmaxf(acc[q].x, acc[q].y), fmaxf(acc[q].z, acc[q].w)));
    float ssum = 0.0f;
#pragma unroll
    for (int q = 0; q < 10; ++q)
        ssum += __expf(acc[q].x - m) + __expf(acc[q].y - m) +
                __expf(acc[q].z - m) + __expf(acc[q].w - m);
    float lse = m + __logf(ssum);
    float4* op = (float4*)(out + (size_t)n * C);
#pragma unroll
    for (int q = 0; q < 10; ++q) {
        float4 v;
        v.x = acc[q].x - lse; v.y = acc[q].y - lse;
        v.z = acc[q].z - lse; v.w = acc[q].w - lse;
        op[q] = v;
    }
}

extern "C" void kernel_launch(void* const* d_in, const int* in_sizes, int n_in,
                              void* d_out, int out_size, void* d_ws, size_t ws_size,
                              hipStream_t stream) {
    const float* x     = (const float*)d_in[0];
    const int*   index = (const int*)d_in[1];
    const float* wl    = (const float*)d_in[2];
    const float* bl    = (const float*)d_in[3];
    const float* wr    = (const float*)d_in[4];
    float* out = (float*)d_out;

    int nedges = in_sizes[1] / 2;
    const int* src = index;
    const int* dst = index + nedges;

    // ws: [y N*C f][bbuf NB*BCAP i][sorted_src E i][off N i][deg N i][gcursor NBPAD i]
    size_t need = ((size_t)NODES * C + (size_t)NB * BCAP + (size_t)nedges
                   + 2 * (size_t)NODES + NBPAD) * 4;

    if (ws_size >= need) {
        float* y        = (float*)d_ws;
        int* bbuf       = (int*)(y + (size_t)NODES * C);
        int* sorted_src = bbuf + (size_t)NB * BCAP;
        int* off        = sorted_src + nedges;
        int* deg        = off + NODES;
        int* gcursor    = deg + NODES;

        hipMemsetAsync(gcursor, 0, NBPAD * sizeof(int), stream);

        int nblk = (NODES + 255) / 256;
        precompute_yz<<<nblk, 256, 0, stream>>>(x, wl, bl, wr, y, out);
        bucketize<<<(nedges + TILE - 1) / TILE, 256, 0, stream>>>(
            src, dst, gcursor, bbuf, nedges);
        local_sort<<<NB, 256, 0, stream>>>(bbuf, gcursor, sorted_src, off, deg);
        aggregate_y<<<(NODES + 3) / 4, 256, 0, stream>>>(
            y, sorted_src, off, deg, out);
    } else {
        float* aggsum = (float*)d_ws;
        float* deg    = aggsum + (size_t)NODES * F;
        hipMemsetAsync(d_ws, 0,
                       ((size_t)NODES * F + NODES) * sizeof(float), stream);
        scatter_kernel<<<(nedges + 3) / 4, 256, 0, stream>>>(
            x, src, dst, aggsum, deg, nedges);
        meanify_kernel<<<(NODES + 3) / 4, 256, 0, stream>>>(aggsum, deg);
        node_kernel<<<(NODES + 255) / 256, 256, 0, stream>>>(
            x, aggsum, wl, bl, wr, out);
    }
}

// Round 7
// 219.278 us; speedup vs baseline: 2.1035x; 1.1843x over previous
//
#include <hip/hip_runtime.h>
#include <math.h>

constexpr int NODES = 100000;
constexpr int F = 64;       // features
constexpr int C = 40;       // classes
constexpr int NPB   = 128;                     // nodes per bucket
constexpr int NB    = (NODES + NPB - 1) / NPB; // 782 buckets
constexpr int NBPAD = 1024;
constexpr int BCAP  = 2816;    // per-bucket cap (mean 2046, sigma ~45: +17 sigma)
constexpr int TILE  = 4096;    // edges per bucketize block

// ===========================================================================
// K1: y = x @ Wl ; out(z) = x @ Wr + b.  Weights read at wave-uniform global
// addresses -> compiler scalarizes to s_load (scalar pipe), no LDS pipe tax.
// ===========================================================================
__global__ __launch_bounds__(256)
void precompute_yz(const float* __restrict__ x,
                   const float* __restrict__ wl,
                   const float* __restrict__ bl,
                   const float* __restrict__ wr,
                   float* __restrict__ y,
                   float* __restrict__ out) {
    int n = blockIdx.x * 256 + threadIdx.x;
    if (n >= NODES) return;

    float4 ya[10], za[10];
    const float4* bl4 = (const float4*)bl;    // uniform -> s_load
#pragma unroll
    for (int q = 0; q < 10; ++q) {
        ya[q] = make_float4(0.f, 0.f, 0.f, 0.f);
        za[q] = bl4[q];
    }
    const float4* xr  = (const float4*)(x + (size_t)n * F);
    const float4* wl4 = (const float4*)wl;    // uniform indices -> s_load
    const float4* wr4 = (const float4*)wr;

    for (int f4 = 0; f4 < F / 4; ++f4) {      // not unrolled: keep I$ small
        float4 xv = xr[f4];
        float xs[4] = {xv.x, xv.y, xv.z, xv.w};
#pragma unroll
        for (int jj = 0; jj < 4; ++jj) {
            int f = f4 * 4 + jj;
            float xf = xs[jj];
#pragma unroll
            for (int q = 0; q < 10; ++q) {
                float4 wlv = wl4[f * 10 + q];
                float4 wrv = wr4[f * 10 + q];
                ya[q].x = fmaf(xf, wlv.x, ya[q].x);
                ya[q].y = fmaf(xf, wlv.y, ya[q].y);
                ya[q].z = fmaf(xf, wlv.z, ya[q].z);
                ya[q].w = fmaf(xf, wlv.w, ya[q].w);
                za[q].x = fmaf(xf, wrv.x, za[q].x);
                za[q].y = fmaf(xf, wrv.y, za[q].y);
                za[q].z = fmaf(xf, wrv.z, za[q].z);
                za[q].w = fmaf(xf, wrv.w, za[q].w);
            }
        }
    }
    float4* yp = (float4*)(y   + (size_t)n * C);
    float4* zp = (float4*)(out + (size_t)n * C);
#pragma unroll
    for (int q = 0; q < 10; ++q) { yp[q] = ya[q]; zp[q] = za[q]; }
}

// ===========================================================================
// K2: bucketize edges by dst>>7 into 782 dense streams.
// pack = src(17b) | dlow(7b)<<17
// ===========================================================================
__global__ __launch_bounds__(256)
void bucketize(const int* __restrict__ src, const int* __restrict__ dst,
               int* __restrict__ gcursor, int* __restrict__ bbuf, int nedges) {
    __shared__ int lhist[NB];
    __shared__ int lcur[NB];
    int t = threadIdx.x;
    for (int i = t; i < NB; i += 256) lhist[i] = 0;
    __syncthreads();

    int base = blockIdx.x * TILE;
    int pk[16], bk[16];
#pragma unroll
    for (int u = 0; u < 16; ++u) {
        int e = base + u * 256 + t;
        bk[u] = -1;
        if (e < nedges) {
            int s = src[e], d = dst[e];
            if ((unsigned)s < (unsigned)NODES && (unsigned)d < (unsigned)NODES) {
                bk[u] = d >> 7;
                pk[u] = s | ((d & 127) << 17);
                atomicAdd(&lhist[bk[u]], 1);
            }
        }
    }
    __syncthreads();
    for (int i = t; i < NB; i += 256) {
        int c = lhist[i];
        lcur[i] = c ? atomicAdd(&gcursor[i], c) : 0;   // bucket-relative base
    }
    __syncthreads();
#pragma unroll
    for (int u = 0; u < 16; ++u) {
        if (bk[u] >= 0) {
            int p = atomicAdd(&lcur[bk[u]], 1);
            if (p < BCAP) bbuf[(size_t)bk[u] * BCAP + p] = pk[u];
        }
    }
}

// ===========================================================================
// K3: block per bucket (782): 128-counter LDS hist -> scan -> dense deg/off
// -> scatter src into the global dst-sorted CSR (8KB single-CU window).
// ===========================================================================
__global__ __launch_bounds__(256)
void local_sort(const int* __restrict__ bbuf, const int* __restrict__ gcount,
                int* __restrict__ sorted_src, int* __restrict__ off,
                int* __restrict__ deg) {
    __shared__ int lhist[NPB];
    __shared__ int lcur[NPB];
    __shared__ int wred[4];
    __shared__ int w0tot;

    int b = blockIdx.x;
    int t = threadIdx.x;
    int lane = t & 63, wv = t >> 6;

    // ebase = sum_{i<b} gcount[i] : strided partials + block reduce
    int part = 0;
    for (int i = t; i < b; i += 256) part += gcount[i];
#pragma unroll
    for (int d = 1; d < 64; d <<= 1) part += __shfl_xor(part, d);
    if (lane == 0) wred[wv] = part;
    if (t < NPB) lhist[t] = 0;
    __syncthreads();
    int ebase = wred[0] + wred[1] + wred[2] + wred[3];

    int cnt = gcount[b];
    if (cnt > BCAP) cnt = BCAP;
    const int* myb = bbuf + (size_t)b * BCAP;

    for (int i = t; i < cnt; i += 256)
        atomicAdd(&lhist[myb[i] >> 17], 1);
    __syncthreads();

    // exclusive scan of lhist[0..127] (waves 0,1), then per-node deg/off
    int c = 0, sc = 0;
    if (t < NPB) {
        c = lhist[t];
        sc = c;
#pragma unroll
        for (int d = 1; d < 64; d <<= 1) {
            int o = __shfl_up(sc, d);
            if (lane >= d) sc += o;
        }
    }
    if (t == 63) w0tot = sc;
    __syncthreads();
    if (t >= 64 && t < NPB) sc += w0tot;
    if (t < NPB) {
        int excl = ebase + sc - c;
        lcur[t] = excl;
        int n = b * NPB + t;
        if (n < NODES) { off[n] = excl; deg[n] = c; }
    }
    __syncthreads();

    for (int i = t; i < cnt; i += 256) {
        int pk = myb[i];
        int p = atomicAdd(&lcur[pk >> 17], 1);
        sorted_src[p] = pk & 0x1FFFF;
    }
}

// ===========================================================================
// K4: wave per node, lane = class. Unpredicated 8-deep main loop + one
// masked tail block; add z (in out), log_softmax.
// ===========================================================================
__global__ __launch_bounds__(256)
void aggregate_y(const float* __restrict__ y,
                 const int* __restrict__ sorted_src,
                 const int* __restrict__ off,
                 const int* __restrict__ deg,
                 float* __restrict__ out) {
    int t = threadIdx.x;
    int lane = t & 63;
    int n = blockIdx.x * 4 + (t >> 6);
    if (n >= NODES) return;

    int base = off[n];
    int cnt  = deg[n];
    int cc = lane < C ? lane : C - 1;

    float acc = 0.0f;
    int full = cnt & ~7;
    int j = 0;
    for (; j < full; j += 8) {               // no predication in the hot loop
        int s0 = sorted_src[base + j + 0];
        int s1 = sorted_src[base + j + 1];
        int s2 = sorted_src[base + j + 2];
        int s3 = sorted_src[base + j + 3];
        int s4 = sorted_src[base + j + 4];
        int s5 = sorted_src[base + j + 5];
        int s6 = sorted_src[base + j + 6];
        int s7 = sorted_src[base + j + 7];
        float v0 = y[(size_t)s0 * C + cc];
        float v1 = y[(size_t)s1 * C + cc];
        float v2 = y[(size_t)s2 * C + cc];
        float v3 = y[(size_t)s3 * C + cc];
        float v4 = y[(size_t)s4 * C + cc];
        float v5 = y[(size_t)s5 * C + cc];
        float v6 = y[(size_t)s6 * C + cc];
        float v7 = y[(size_t)s7 * C + cc];
        acc += ((v0 + v1) + (v2 + v3)) + ((v4 + v5) + (v6 + v7));
    }
    if (j < cnt) {                           // single masked tail block
#pragma unroll
        for (int u = 0; u < 8; ++u) {
            int e = j + u;
            int ec = e < cnt ? e : cnt - 1;
            int s = sorted_src[base + ec];
            float v = y[(size_t)s * C + cc];
            acc += (e < cnt) ? v : 0.0f;
        }
    }
    float inv = 1.0f / (float)(cnt > 0 ? cnt : 1);

    float o = 0.0f;
    if (lane < C) o = out[(size_t)n * C + lane] + acc * inv;

    float mv = lane < C ? o : -1e30f;
#pragma unroll
    for (int d = 1; d < 64; d <<= 1) mv = fmaxf(mv, __shfl_xor(mv, d));
    float ev = lane < C ? __expf(o - mv) : 0.0f;
#pragma unroll
    for (int d = 1; d < 64; d <<= 1) ev += __shfl_xor(ev, d);
    float lse = mv + __logf(ev);

    if (lane < C) out[(size_t)n * C + lane] = o - lse;
}

// ===========================================================================
// Fallback path (R1) if workspace too small
// ===========================================================================
__global__ __launch_bounds__(256)
void scatter_kernel(const float* __restrict__ x, const int* __restrict__ src,
                    const int* __restrict__ dst, float* __restrict__ aggsum,
                    float* __restrict__ deg, int nedges) {
    int lane = threadIdx.x & 63;
    int e = blockIdx.x * 4 + (threadIdx.x >> 6);
    if (e >= nedges) return;
    int s = src[e], d = dst[e];
    if ((unsigned)s >= (unsigned)NODES || (unsigned)d >= (unsigned)NODES) return;
    atomicAdd(&aggsum[(size_t)d * F + lane], x[(size_t)s * F + lane]);
    if (lane == 0) atomicAdd(&deg[d], 1.0f);
}

__global__ __launch_bounds__(256)
void meanify_kernel(float* __restrict__ aggsum, const float* __restrict__ deg) {
    int lane = threadIdx.x & 63;
    int n = blockIdx.x * 4 + (threadIdx.x >> 6);
    if (n >= NODES) return;
    aggsum[(size_t)n * F + lane] *= 1.0f / fmaxf(deg[n], 1.0f);
}

__global__ __launch_bounds__(256)
void node_kernel(const float* __restrict__ x, const float* __restrict__ aggmean,
                 const float* __restrict__ wl, const float* __restrict__ bl,
                 const float* __restrict__ wr, float* __restrict__ out) {
    __shared__ alignas(16) float sWl[F * C];
    __shared__ alignas(16) float sWr[F * C];
    __shared__ alignas(16) float sb[C];
    for (int i = threadIdx.x; i < F * C; i += 256) { sWl[i] = wl[i]; sWr[i] = wr[i]; }
    if (threadIdx.x < C) sb[threadIdx.x] = bl[threadIdx.x];
    __syncthreads();
    int n = blockIdx.x * 256 + threadIdx.x;
    if (n >= NODES) return;
    float4 acc[10];
    const float4* sb4 = (const float4*)sb;
#pragma unroll
    for (int q = 0; q < 10; ++q) acc[q] = sb4[q];
    const float4* xr  = (const float4*)(x       + (size_t)n * F);
    const float4* ar  = (const float4*)(aggmean + (size_t)n * F);
    const float4* wl4 = (const float4*)sWl;
    const float4* wr4 = (const float4*)sWr;
    for (int f4 = 0; f4 < F / 4; ++f4) {
        float4 xv = xr[f4], av = ar[f4];
        float xs[4]  = {xv.x, xv.y, xv.z, xv.w};
        float as_[4] = {av.x, av.y, av.z, av.w};
#pragma unroll
        for (int jj = 0; jj < 4; ++jj) {
            int f = f4 * 4 + jj;
#pragma unroll
            for (int q = 0; q < 10; ++q) {
                float4 wlv = wl4[f * 10 + q], wrv = wr4[f * 10 + q];
                acc[q].x = fmaf(as_[jj], wlv.x, fmaf(xs[jj], wrv.x, acc[q].x));
                acc[q].y = fmaf(as_[jj], wlv.y, fmaf(xs[jj], wrv.y, acc[q].y));
                acc[q].z = fmaf(as_[jj], wlv.z, fmaf(xs[jj], wrv.z, acc[q].z));
                acc[q].w = fmaf(as_[jj], wlv.w, fmaf(xs[jj], wrv.w, acc[q].w));
            }
        }
    }
    float m = -1e30f;
#pragma unroll
    for (int q = 0; q < 10; ++q)
        m = fmaxf(m, fmaxf(fmaxf(acc[q].x, acc[q].y), fmaxf(acc[q].z, acc[q].w)));
    float ssum = 0.0f;
#pragma unroll
    for (int q = 0; q < 10; ++q)
        ssum += __expf(acc[q].x - m) + __expf(acc[q].y - m) +
                __expf(acc[q].z - m) + __expf(acc[q].w - m);
    float lse = m + __logf(ssum);
    float4* op = (float4*)(out + (size_t)n * C);
#pragma unroll
    for (int q = 0; q < 10; ++q) {
        float4 v;
        v.x = acc[q].x - lse; v.y = acc[q].y - lse;
        v.z = acc[q].z - lse; v.w = acc[q].w - lse;
        op[q] = v;
    }
}

extern "C" void kernel_launch(void* const* d_in, const int* in_sizes, int n_in,
                              void* d_out, int out_size, void* d_ws, size_t ws_size,
                              hipStream_t stream) {
    const float* x     = (const float*)d_in[0];
    const int*   index = (const int*)d_in[1];
    const float* wl    = (const float*)d_in[2];
    const float* bl    = (const float*)d_in[3];
    const float* wr    = (const float*)d_in[4];
    float* out = (float*)d_out;

    int nedges = in_sizes[1] / 2;
    const int* src = index;
    const int* dst = index + nedges;

    // ws: [y N*C f][bbuf NB*BCAP i][sorted_src E i][off N i][deg N i][gcursor NBPAD i]
    size_t need = ((size_t)NODES * C + (size_t)NB * BCAP + (size_t)nedges
                   + 2 * (size_t)NODES + NBPAD) * 4;

    if (ws_size >= need) {
        float* y        = (float*)d_ws;
        int* bbuf       = (int*)(y + (size_t)NODES * C);
        int* sorted_src = bbuf + (size_t)NB * BCAP;
        int* off        = sorted_src + nedges;
        int* deg        = off + NODES;
        int* gcursor    = deg + NODES;

        hipMemsetAsync(gcursor, 0, NBPAD * sizeof(int), stream);

        int nblk = (NODES + 255) / 256;
        bucketize<<<(nedges + TILE - 1) / TILE, 256, 0, stream>>>(
            src, dst, gcursor, bbuf, nedges);
        local_sort<<<NB, 256, 0, stream>>>(bbuf, gcursor, sorted_src, off, deg);
        precompute_yz<<<nblk, 256, 0, stream>>>(x, wl, bl, wr, y, out);
        aggregate_y<<<(NODES + 3) / 4, 256, 0, stream>>>(
            y, sorted_src, off, deg, out);
    } else {
        float* aggsum = (float*)d_ws;
        float* deg    = aggsum + (size_t)NODES * F;
        hipMemsetAsync(d_ws, 0,
                       ((size_t)NODES * F + NODES) * sizeof(float), stream);
        scatter_kernel<<<(nedges + 3) / 4, 256, 0, stream>>>(
            x, src, dst, aggsum, deg, nedges);
        meanify_kernel<<<(NODES + 3) / 4, 256, 0, stream>>>(aggsum, deg);
        node_kernel<<<(NODES + 255) / 256, 256, 0, stream>>>(
            x, aggsum, wl, bl, wr, out);
    }
}